// Round 1
// baseline (2588.828 us; speedup 1.0000x reference)
//
#include <hip/hip_runtime.h>
#include <hip/hip_bf16.h>

#define H      128
#define NNODE  50000
#define NLINK  100000
#define NEDGE  600000
#define NGRAPH 32
#define NLAYER 4
#define LT     16   // rows (links/nodes) per block tile in update_k

// ---------------- CSR build ----------------

__global__ void count_edges_k(const int* __restrict__ nl_dst, const int* __restrict__ ln_dst,
                              int* __restrict__ cnt_link, int* __restrict__ cnt_node) {
    int i = blockIdx.x * blockDim.x + threadIdx.x;
    int stride = gridDim.x * blockDim.x;
    for (; i < NEDGE; i += stride) {
        atomicAdd(&cnt_link[nl_dst[i]], 1);
        atomicAdd(&cnt_node[ln_dst[i]], 1);
    }
}

// hierarchical exclusive scan: 1024 elements per block, 256 threads
__global__ void scan_sums_k(const int* __restrict__ in, int n, int* __restrict__ bsums) {
    __shared__ int sd[256];
    int base = blockIdx.x * 1024;
    int s = 0;
    for (int i = threadIdx.x; i < 1024; i += 256) {
        int idx = base + i;
        if (idx < n) s += in[idx];
    }
    sd[threadIdx.x] = s;
    __syncthreads();
    for (int off = 128; off; off >>= 1) {
        if (threadIdx.x < off) sd[threadIdx.x] += sd[threadIdx.x + off];
        __syncthreads();
    }
    if (threadIdx.x == 0) bsums[blockIdx.x] = sd[0];
}

__global__ void scan_bsums_k(int* __restrict__ bsums, int nb) {
    __shared__ int tmp[2][1024];
    int t = threadIdx.x;
    int v = (t < nb) ? bsums[t] : 0;
    int src = 0;
    tmp[0][t] = v;
    __syncthreads();
    for (int off = 1; off < 1024; off <<= 1) {
        int nv = tmp[src][t] + ((t >= off) ? tmp[src][t - off] : 0);
        tmp[src ^ 1][t] = nv;
        __syncthreads();
        src ^= 1;
    }
    if (t < nb) bsums[t] = tmp[src][t] - v;  // exclusive
}

__global__ void scan_final_k(const int* __restrict__ in, int n, const int* __restrict__ bsums,
                             int* __restrict__ out, int total) {
    __shared__ int tmp[2][256];
    int b = blockIdx.x, t = threadIdx.x;
    int base = b * 1024 + t * 4;
    int vals[4];
    int s = 0;
#pragma unroll
    for (int j = 0; j < 4; ++j) {
        int idx = base + j;
        vals[j] = (idx < n) ? in[idx] : 0;
        s += vals[j];
    }
    tmp[0][t] = s;
    __syncthreads();
    int src = 0;
    for (int off = 1; off < 256; off <<= 1) {
        int nv = tmp[src][t] + ((t >= off) ? tmp[src][t - off] : 0);
        tmp[src ^ 1][t] = nv;
        __syncthreads();
        src ^= 1;
    }
    int run = bsums[b] + tmp[src][t] - s;  // exclusive prefix for this thread's 4 elems
#pragma unroll
    for (int j = 0; j < 4; ++j) {
        int idx = base + j;
        if (idx < n) out[idx] = run;
        run += vals[j];
    }
    if (b == 0 && t == 0) out[n] = total;
}

__global__ void fill_csr_k(const int* __restrict__ dst, const int* __restrict__ src,
                           const int* __restrict__ rowp, int* __restrict__ cursor,
                           int* __restrict__ col) {
    int i = blockIdx.x * blockDim.x + threadIdx.x;
    int stride = gridDim.x * blockDim.x;
    for (; i < NEDGE; i += stride) {
        int d = dst[i];
        int pos = rowp[d] + atomicAdd(&cursor[d], 1);
        col[pos] = src[i];
    }
}

__global__ void inv_k(const int* __restrict__ cnt, float* __restrict__ inv, int n) {
    int i = blockIdx.x * blockDim.x + threadIdx.x;
    if (i < n) {
        int c = cnt[i];
        inv[i] = 1.0f / (float)(c > 0 ? c : 1);
    }
}

__global__ void batch_ranges_k(const int* __restrict__ batch, int* __restrict__ gstart,
                               float* __restrict__ ginv) {
    __shared__ int ss[NGRAPH + 1];
    int g = threadIdx.x;
    if (g <= NGRAPH) {
        int lo = 0, hi = NLINK;
        while (lo < hi) {
            int mid = (lo + hi) >> 1;
            if (batch[mid] < g) lo = mid + 1; else hi = mid;
        }
        ss[g] = lo;
        gstart[g] = lo;
    }
    __syncthreads();
    if (g < NGRAPH) {
        int c = ss[g + 1] - ss[g];
        ginv[g] = 1.0f / (float)(c > 0 ? c : 1);
    }
}

// ---------------- fused aggregate + linear + relu ----------------
// out[row, :] = relu( concat(mean_{e in CSR row} xsrc[col[e]], xself[row]) @ W + b )
__global__ __launch_bounds__(256) void update_k(
    const float* __restrict__ xsrc, const float* __restrict__ xself,
    const int* __restrict__ rowp, const int* __restrict__ colx,
    const float* __restrict__ invdeg, const float* __restrict__ W,
    const float* __restrict__ bias, float* __restrict__ out, int ndst) {
    __shared__ float tile[LT][2 * H];
    const int tid = threadIdx.x;
    const int od = tid & 127;    // output dim / feature dim
    const int lg = tid >> 7;     // 0 or 1
    const float bv = bias[od];

    for (int t0 = blockIdx.x * LT; t0 < ndst; t0 += gridDim.x * LT) {
        // phase 1: build [agg | self] input tile (coalesced 512B row gathers)
        for (int j = 0; j < 8; ++j) {
            int lsub = lg + j * 2;
            int row = t0 + lsub;
            float aggv = 0.f, selfv = 0.f;
            if (row < ndst) {
                int rs = rowp[row], re = rowp[row + 1];
                float ssum = 0.f;
                for (int e = rs; e < re; ++e)
                    ssum += xsrc[(size_t)colx[e] * H + od];
                aggv = ssum * invdeg[row];
                selfv = xself[(size_t)row * H + od];
            }
            tile[lsub][od] = aggv;
            tile[lsub][H + od] = selfv;
        }
        __syncthreads();

        // phase 2: 16x256 @ 256x128 ; each thread: 8 rows x 1 outdim
        float acc[8] = {0.f, 0.f, 0.f, 0.f, 0.f, 0.f, 0.f, 0.f};
#pragma unroll 4
        for (int k4 = 0; k4 < 64; ++k4) {
            int k = k4 * 4;
            float w0 = W[(size_t)(k + 0) * H + od];
            float w1 = W[(size_t)(k + 1) * H + od];
            float w2 = W[(size_t)(k + 2) * H + od];
            float w3 = W[(size_t)(k + 3) * H + od];
#pragma unroll
            for (int j = 0; j < 8; ++j) {
                float4 v = *reinterpret_cast<const float4*>(&tile[lg * 8 + j][k]);
                acc[j] = fmaf(v.x, w0, acc[j]);
                acc[j] = fmaf(v.y, w1, acc[j]);
                acc[j] = fmaf(v.z, w2, acc[j]);
                acc[j] = fmaf(v.w, w3, acc[j]);
            }
        }
#pragma unroll
        for (int j = 0; j < 8; ++j) {
            int row = t0 + lg * 8 + j;
            if (row < ndst) {
                float r = acc[j] + bv;
                out[(size_t)row * H + od] = fmaxf(r, 0.f);
            }
        }
        __syncthreads();
    }
}

// ---------------- final global mean pool over links ----------------
__global__ void pool_k(const float* __restrict__ xl, const int* __restrict__ gstart,
                       const float* __restrict__ ginv, float* __restrict__ out) {
    const int CH = 8;
    int g = blockIdx.x / CH, c = blockIdx.x % CH;
    int s = gstart[g], e = gstart[g + 1];
    int d = threadIdx.x & 127, h = threadIdx.x >> 7;
    float sum = 0.f;
    for (int l = s + c * 2 + h; l < e; l += CH * 2)
        sum += xl[(size_t)l * H + d];
    __shared__ float sm[256];
    sm[threadIdx.x] = sum;
    __syncthreads();
    if (h == 0) {
        float tot = sum + sm[128 + d];
        atomicAdd(&out[g * H + d], tot * ginv[g]);
    }
}

// ---------------- host ----------------

extern "C" void kernel_launch(void* const* d_in, const int* in_sizes, int n_in,
                              void* d_out, int out_size, void* d_ws, size_t ws_size,
                              hipStream_t stream) {
    const float* x_node = (const float*)d_in[0];
    const float* x_link = (const float*)d_in[1];
    const int* nl_src = (const int*)d_in[2];
    const int* nl_dst = (const int*)d_in[3];
    const int* ln_src = (const int*)d_in[4];
    const int* ln_dst = (const int*)d_in[5];
    const int* batch = (const int*)d_in[6];
    const float* W_nl = (const float*)d_in[7];
    const float* b_nl = (const float*)d_in[8];
    const float* W_ln = (const float*)d_in[9];
    const float* b_ln = (const float*)d_in[10];
    float* out = (float*)d_out;

    char* ws = (char*)d_ws;
    size_t off = 0;
    auto alloc = [&](size_t bytes) -> void* {
        void* p = ws + off;
        off += (bytes + 255) & ~(size_t)255;
        return p;
    };
    float* xl0 = (float*)alloc((size_t)NLINK * H * 4);
    float* xl1 = (float*)alloc((size_t)NLINK * H * 4);
    float* xn0 = (float*)alloc((size_t)NNODE * H * 4);
    float* xn1 = (float*)alloc((size_t)NNODE * H * 4);
    int* rowp_link = (int*)alloc((size_t)(NLINK + 1) * 4);
    int* rowp_node = (int*)alloc((size_t)(NNODE + 1) * 4);
    int* col_nl = (int*)alloc((size_t)NEDGE * 4);
    int* col_ln = (int*)alloc((size_t)NEDGE * 4);
    int* cnts = (int*)alloc((size_t)(2 * (NLINK + NNODE)) * 4);
    int* cnt_link = cnts;
    int* cnt_node = cnts + NLINK;
    int* cur_link = cnt_node + NNODE;
    int* cur_node = cur_link + NLINK;
    float* inv_link = (float*)alloc((size_t)NLINK * 4);
    float* inv_node = (float*)alloc((size_t)NNODE * 4);
    int* bsums = (int*)alloc(1024 * 4);
    int* gstart = (int*)alloc((NGRAPH + 1) * 4);
    float* ginv = (float*)alloc(NGRAPH * 4);

    if (off > ws_size) return;  // workspace too small -> fail loudly (poisoned out)

    hipMemsetAsync(cnts, 0, (size_t)(2 * (NLINK + NNODE)) * 4, stream);
    hipMemsetAsync(out, 0, (size_t)NGRAPH * H * 4, stream);

    count_edges_k<<<1024, 256, 0, stream>>>(nl_dst, ln_dst, cnt_link, cnt_node);

    int nbL = (NLINK + 1023) / 1024;
    scan_sums_k<<<nbL, 256, 0, stream>>>(cnt_link, NLINK, bsums);
    scan_bsums_k<<<1, 1024, 0, stream>>>(bsums, nbL);
    scan_final_k<<<nbL, 256, 0, stream>>>(cnt_link, NLINK, bsums, rowp_link, NEDGE);

    int nbN = (NNODE + 1023) / 1024;
    scan_sums_k<<<nbN, 256, 0, stream>>>(cnt_node, NNODE, bsums);
    scan_bsums_k<<<1, 1024, 0, stream>>>(bsums, nbN);
    scan_final_k<<<nbN, 256, 0, stream>>>(cnt_node, NNODE, bsums, rowp_node, NEDGE);

    inv_k<<<(NLINK + 255) / 256, 256, 0, stream>>>(cnt_link, inv_link, NLINK);
    inv_k<<<(NNODE + 255) / 256, 256, 0, stream>>>(cnt_node, inv_node, NNODE);

    fill_csr_k<<<1024, 256, 0, stream>>>(nl_dst, nl_src, rowp_link, cur_link, col_nl);
    fill_csr_k<<<1024, 256, 0, stream>>>(ln_dst, ln_src, rowp_node, cur_node, col_ln);

    batch_ranges_k<<<1, 64, 0, stream>>>(batch, gstart, ginv);

    const float* xlin = x_link;
    const float* xnin = x_node;
    float* xlb[2] = {xl0, xl1};
    float* xnb[2] = {xn0, xn1};
    for (int i = 0; i < NLAYER; ++i) {
        float* xlo = xlb[i & 1];
        float* xno = xnb[i & 1];
        update_k<<<(NLINK + LT - 1) / LT, 256, 0, stream>>>(
            xnin, xlin, rowp_link, col_nl, inv_link,
            W_nl + (size_t)i * 2 * H * H, b_nl + (size_t)i * H, xlo, NLINK);
        update_k<<<(NNODE + LT - 1) / LT, 256, 0, stream>>>(
            xlin, xnin, rowp_node, col_ln, inv_node,
            W_ln + (size_t)i * 2 * H * H, b_ln + (size_t)i * H, xno, NNODE);
        xlin = xlo;
        xnin = xno;
    }

    pool_k<<<NGRAPH * 8, 256, 0, stream>>>(xlin, gstart, ginv, out);
}

// Round 2
// 1511.992 us; speedup vs baseline: 1.7122x; 1.7122x over previous
//
#include <hip/hip_runtime.h>
#include <hip/hip_bf16.h>

#define H      128
#define NNODE  50000
#define NLINK  100000
#define NEDGE  600000
#define NGRAPH 32
#define NLAYER 4
#define LT     32   // rows (links/nodes) per block tile in update_k

// ---------------- CSR build ----------------

__global__ void count_edges_k(const int* __restrict__ nl_dst, const int* __restrict__ ln_dst,
                              int* __restrict__ cnt_link, int* __restrict__ cnt_node) {
    int i = blockIdx.x * blockDim.x + threadIdx.x;
    int stride = gridDim.x * blockDim.x;
    for (; i < NEDGE; i += stride) {
        atomicAdd(&cnt_link[nl_dst[i]], 1);
        atomicAdd(&cnt_node[ln_dst[i]], 1);
    }
}

// hierarchical exclusive scan: 1024 elements per block, 256 threads
__global__ void scan_sums_k(const int* __restrict__ in, int n, int* __restrict__ bsums) {
    __shared__ int sd[256];
    int base = blockIdx.x * 1024;
    int s = 0;
    for (int i = threadIdx.x; i < 1024; i += 256) {
        int idx = base + i;
        if (idx < n) s += in[idx];
    }
    sd[threadIdx.x] = s;
    __syncthreads();
    for (int off = 128; off; off >>= 1) {
        if (threadIdx.x < off) sd[threadIdx.x] += sd[threadIdx.x + off];
        __syncthreads();
    }
    if (threadIdx.x == 0) bsums[blockIdx.x] = sd[0];
}

__global__ void scan_bsums_k(int* __restrict__ bsums, int nb) {
    __shared__ int tmp[2][1024];
    int t = threadIdx.x;
    int v = (t < nb) ? bsums[t] : 0;
    int src = 0;
    tmp[0][t] = v;
    __syncthreads();
    for (int off = 1; off < 1024; off <<= 1) {
        int nv = tmp[src][t] + ((t >= off) ? tmp[src][t - off] : 0);
        tmp[src ^ 1][t] = nv;
        __syncthreads();
        src ^= 1;
    }
    if (t < nb) bsums[t] = tmp[src][t] - v;  // exclusive
}

__global__ void scan_final_k(const int* __restrict__ in, int n, const int* __restrict__ bsums,
                             int* __restrict__ out, int total) {
    __shared__ int tmp[2][256];
    int b = blockIdx.x, t = threadIdx.x;
    int base = b * 1024 + t * 4;
    int vals[4];
    int s = 0;
#pragma unroll
    for (int j = 0; j < 4; ++j) {
        int idx = base + j;
        vals[j] = (idx < n) ? in[idx] : 0;
        s += vals[j];
    }
    tmp[0][t] = s;
    __syncthreads();
    int src = 0;
    for (int off = 1; off < 256; off <<= 1) {
        int nv = tmp[src][t] + ((t >= off) ? tmp[src][t - off] : 0);
        tmp[src ^ 1][t] = nv;
        __syncthreads();
        src ^= 1;
    }
    int run = bsums[b] + tmp[src][t] - s;  // exclusive prefix for this thread's 4 elems
#pragma unroll
    for (int j = 0; j < 4; ++j) {
        int idx = base + j;
        if (idx < n) out[idx] = run;
        run += vals[j];
    }
    if (b == 0 && t == 0) out[n] = total;
}

__global__ void fill_csr_k(const int* __restrict__ dst, const int* __restrict__ src,
                           const int* __restrict__ rowp, int* __restrict__ cursor,
                           int* __restrict__ col) {
    int i = blockIdx.x * blockDim.x + threadIdx.x;
    int stride = gridDim.x * blockDim.x;
    for (; i < NEDGE; i += stride) {
        int d = dst[i];
        int pos = rowp[d] + atomicAdd(&cursor[d], 1);
        col[pos] = src[i];
    }
}

__global__ void inv_k(const int* __restrict__ cnt, float* __restrict__ inv, int n) {
    int i = blockIdx.x * blockDim.x + threadIdx.x;
    if (i < n) {
        int c = cnt[i];
        inv[i] = 1.0f / (float)(c > 0 ? c : 1);
    }
}

__global__ void batch_ranges_k(const int* __restrict__ batch, int* __restrict__ gstart,
                               float* __restrict__ ginv) {
    __shared__ int ss[NGRAPH + 1];
    int g = threadIdx.x;
    if (g <= NGRAPH) {
        int lo = 0, hi = NLINK;
        while (lo < hi) {
            int mid = (lo + hi) >> 1;
            if (batch[mid] < g) lo = mid + 1; else hi = mid;
        }
        ss[g] = lo;
        gstart[g] = lo;
    }
    __syncthreads();
    if (g < NGRAPH) {
        int c = ss[g + 1] - ss[g];
        ginv[g] = 1.0f / (float)(c > 0 ? c : 1);
    }
}

// ---------------- fused aggregate + linear + relu ----------------
// out[row, :] = relu( concat(mean_{e in CSR row} xsrc[col[e]], xself[row]) @ W + b )
// 256 threads. Phase 1: 32 threads/row float4 gather, 8 rows in flight.
// Phase 2: 32x256 @ 256x128, thread tile = 8 rows x 2 adjacent outdims.
__global__ __launch_bounds__(256) void update_k(
    const float* __restrict__ xsrc, const float* __restrict__ xself,
    const int* __restrict__ rowp, const int* __restrict__ colx,
    const float* __restrict__ invdeg, const float* __restrict__ W,
    const float* __restrict__ bias, float* __restrict__ out, int ndst) {
    __shared__ float tile[LT][2 * H];   // 32 KB
    const int tid = threadIdx.x;
    // phase-1 mapping
    const int lane = tid & 31;   // float4 index within a 128-float row
    const int rsub = tid >> 5;   // 0..7
    // phase-2 mapping
    const int odq = tid & 63;    // outdim pair index: od = 2*odq, 2*odq+1
    const int rq = tid >> 6;     // 0..3 -> rows rq*8 .. rq*8+7
    const float2* __restrict__ W2 = reinterpret_cast<const float2*>(W);
    const float2* __restrict__ b2 = reinterpret_cast<const float2*>(bias);
    const float4* __restrict__ xsrc4 = reinterpret_cast<const float4*>(xsrc);
    const float4* __restrict__ xself4 = reinterpret_cast<const float4*>(xself);
    float2* __restrict__ out2 = reinterpret_cast<float2*>(out);
    const float2 bv = b2[odq];

    for (int t0 = blockIdx.x * LT; t0 < ndst; t0 += gridDim.x * LT) {
        // ---- phase 1: build [agg | self] input tile ----
#pragma unroll
        for (int j = 0; j < 4; ++j) {
            int rl = j * 8 + rsub;
            int row = t0 + rl;
            float ax = 0.f, ay = 0.f, az = 0.f, aw = 0.f;
            float bx = 0.f, by = 0.f, bz = 0.f, bw = 0.f;
            float4 sv = {0.f, 0.f, 0.f, 0.f};
            if (row < ndst) {
                int e = rowp[row], re = rowp[row + 1];
                for (; e + 2 <= re; e += 2) {
                    int c0 = colx[e], c1 = colx[e + 1];
                    float4 v0 = xsrc4[(size_t)c0 * 32 + lane];
                    float4 v1 = xsrc4[(size_t)c1 * 32 + lane];
                    ax += v0.x; ay += v0.y; az += v0.z; aw += v0.w;
                    bx += v1.x; by += v1.y; bz += v1.z; bw += v1.w;
                }
                if (e < re) {
                    int c0 = colx[e];
                    float4 v0 = xsrc4[(size_t)c0 * 32 + lane];
                    ax += v0.x; ay += v0.y; az += v0.z; aw += v0.w;
                }
                float inv = invdeg[row];
                ax = (ax + bx) * inv; ay = (ay + by) * inv;
                az = (az + bz) * inv; aw = (aw + bw) * inv;
                sv = xself4[(size_t)row * 32 + lane];
            }
            float4 av = {ax, ay, az, aw};
            *reinterpret_cast<float4*>(&tile[rl][lane * 4]) = av;
            *reinterpret_cast<float4*>(&tile[rl][H + lane * 4]) = sv;
        }
        __syncthreads();

        // ---- phase 2: 32x256 @ 256x128 ----
        float acc0[8] = {0.f, 0.f, 0.f, 0.f, 0.f, 0.f, 0.f, 0.f};
        float acc1[8] = {0.f, 0.f, 0.f, 0.f, 0.f, 0.f, 0.f, 0.f};
#pragma unroll 2
        for (int k4 = 0; k4 < 64; ++k4) {
            int k = k4 * 4;
            float2 w0 = W2[(size_t)(k + 0) * 64 + odq];
            float2 w1 = W2[(size_t)(k + 1) * 64 + odq];
            float2 w2 = W2[(size_t)(k + 2) * 64 + odq];
            float2 w3 = W2[(size_t)(k + 3) * 64 + odq];
#pragma unroll
            for (int r = 0; r < 8; ++r) {
                float4 v = *reinterpret_cast<const float4*>(&tile[rq * 8 + r][k]);
                acc0[r] = fmaf(v.x, w0.x, acc0[r]); acc1[r] = fmaf(v.x, w0.y, acc1[r]);
                acc0[r] = fmaf(v.y, w1.x, acc0[r]); acc1[r] = fmaf(v.y, w1.y, acc1[r]);
                acc0[r] = fmaf(v.z, w2.x, acc0[r]); acc1[r] = fmaf(v.z, w2.y, acc1[r]);
                acc0[r] = fmaf(v.w, w3.x, acc0[r]); acc1[r] = fmaf(v.w, w3.y, acc1[r]);
            }
        }
#pragma unroll
        for (int r = 0; r < 8; ++r) {
            int row = t0 + rq * 8 + r;
            if (row < ndst) {
                float2 o;
                o.x = fmaxf(acc0[r] + bv.x, 0.f);
                o.y = fmaxf(acc1[r] + bv.y, 0.f);
                out2[(size_t)row * 64 + odq] = o;
            }
        }
        __syncthreads();
    }
}

// ---------------- final global mean pool over links ----------------
__global__ void pool_k(const float* __restrict__ xl, const int* __restrict__ gstart,
                       const float* __restrict__ ginv, float* __restrict__ out) {
    const int CH = 8;
    int g = blockIdx.x / CH, c = blockIdx.x % CH;
    int s = gstart[g], e = gstart[g + 1];
    int d = threadIdx.x & 127, h = threadIdx.x >> 7;
    float sum = 0.f;
    for (int l = s + c * 2 + h; l < e; l += CH * 2)
        sum += xl[(size_t)l * H + d];
    __shared__ float sm[256];
    sm[threadIdx.x] = sum;
    __syncthreads();
    if (h == 0) {
        float tot = sum + sm[128 + d];
        atomicAdd(&out[g * H + d], tot * ginv[g]);
    }
}

// ---------------- host ----------------

extern "C" void kernel_launch(void* const* d_in, const int* in_sizes, int n_in,
                              void* d_out, int out_size, void* d_ws, size_t ws_size,
                              hipStream_t stream) {
    const float* x_node = (const float*)d_in[0];
    const float* x_link = (const float*)d_in[1];
    const int* nl_src = (const int*)d_in[2];
    const int* nl_dst = (const int*)d_in[3];
    const int* ln_src = (const int*)d_in[4];
    const int* ln_dst = (const int*)d_in[5];
    const int* batch = (const int*)d_in[6];
    const float* W_nl = (const float*)d_in[7];
    const float* b_nl = (const float*)d_in[8];
    const float* W_ln = (const float*)d_in[9];
    const float* b_ln = (const float*)d_in[10];
    float* out = (float*)d_out;

    char* ws = (char*)d_ws;
    size_t off = 0;
    auto alloc = [&](size_t bytes) -> void* {
        void* p = ws + off;
        off += (bytes + 255) & ~(size_t)255;
        return p;
    };
    float* xl0 = (float*)alloc((size_t)NLINK * H * 4);
    float* xl1 = (float*)alloc((size_t)NLINK * H * 4);
    float* xn0 = (float*)alloc((size_t)NNODE * H * 4);
    float* xn1 = (float*)alloc((size_t)NNODE * H * 4);
    int* rowp_link = (int*)alloc((size_t)(NLINK + 1) * 4);
    int* rowp_node = (int*)alloc((size_t)(NNODE + 1) * 4);
    int* col_nl = (int*)alloc((size_t)NEDGE * 4);
    int* col_ln = (int*)alloc((size_t)NEDGE * 4);
    int* cnts = (int*)alloc((size_t)(2 * (NLINK + NNODE)) * 4);
    int* cnt_link = cnts;
    int* cnt_node = cnts + NLINK;
    int* cur_link = cnt_node + NNODE;
    int* cur_node = cur_link + NLINK;
    float* inv_link = (float*)alloc((size_t)NLINK * 4);
    float* inv_node = (float*)alloc((size_t)NNODE * 4);
    int* bsums = (int*)alloc(1024 * 4);
    int* gstart = (int*)alloc((NGRAPH + 1) * 4);
    float* ginv = (float*)alloc(NGRAPH * 4);

    if (off > ws_size) return;  // workspace too small -> fail loudly (poisoned out)

    hipMemsetAsync(cnts, 0, (size_t)(2 * (NLINK + NNODE)) * 4, stream);
    hipMemsetAsync(out, 0, (size_t)NGRAPH * H * 4, stream);

    count_edges_k<<<1024, 256, 0, stream>>>(nl_dst, ln_dst, cnt_link, cnt_node);

    int nbL = (NLINK + 1023) / 1024;
    scan_sums_k<<<nbL, 256, 0, stream>>>(cnt_link, NLINK, bsums);
    scan_bsums_k<<<1, 1024, 0, stream>>>(bsums, nbL);
    scan_final_k<<<nbL, 256, 0, stream>>>(cnt_link, NLINK, bsums, rowp_link, NEDGE);

    int nbN = (NNODE + 1023) / 1024;
    scan_sums_k<<<nbN, 256, 0, stream>>>(cnt_node, NNODE, bsums);
    scan_bsums_k<<<1, 1024, 0, stream>>>(bsums, nbN);
    scan_final_k<<<nbN, 256, 0, stream>>>(cnt_node, NNODE, bsums, rowp_node, NEDGE);

    inv_k<<<(NLINK + 255) / 256, 256, 0, stream>>>(cnt_link, inv_link, NLINK);
    inv_k<<<(NNODE + 255) / 256, 256, 0, stream>>>(cnt_node, inv_node, NNODE);

    fill_csr_k<<<1024, 256, 0, stream>>>(nl_dst, nl_src, rowp_link, cur_link, col_nl);
    fill_csr_k<<<1024, 256, 0, stream>>>(ln_dst, ln_src, rowp_node, cur_node, col_ln);

    batch_ranges_k<<<1, 64, 0, stream>>>(batch, gstart, ginv);

    const float* xlin = x_link;
    const float* xnin = x_node;
    float* xlb[2] = {xl0, xl1};
    float* xnb[2] = {xn0, xn1};
    for (int i = 0; i < NLAYER; ++i) {
        float* xlo = xlb[i & 1];
        float* xno = xnb[i & 1];
        update_k<<<(NLINK + LT - 1) / LT, 256, 0, stream>>>(
            xnin, xlin, rowp_link, col_nl, inv_link,
            W_nl + (size_t)i * 2 * H * H, b_nl + (size_t)i * H, xlo, NLINK);
        update_k<<<(NNODE + LT - 1) / LT, 256, 0, stream>>>(
            xlin, xnin, rowp_node, col_ln, inv_node,
            W_ln + (size_t)i * 2 * H * H, b_ln + (size_t)i * H, xno, NNODE);
        xlin = xlo;
        xnin = xno;
    }

    pool_k<<<NGRAPH * 8, 256, 0, stream>>>(xlin, gstart, ginv, out);
}

// Round 3
// 1211.777 us; speedup vs baseline: 2.1364x; 1.2477x over previous
//
#include <hip/hip_runtime.h>
#include <hip/hip_bf16.h>

#define H      128
#define NNODE  50000
#define NLINK  100000
#define NEDGE  600000
#define NGRAPH 32
#define NLAYER 4
#define TS     32   // rows per tile in update_mfma_k

typedef short bf16x8 __attribute__((ext_vector_type(8)));
typedef float f32x4 __attribute__((ext_vector_type(4)));

__device__ __forceinline__ ushort f2bf(float f) {
    uint32_t u = __float_as_uint(f);
    uint32_t r = (u + 0x7fff + ((u >> 16) & 1)) >> 16;   // RNE
    return (ushort)r;
}
__device__ __forceinline__ float bf2f(ushort h) {
    return __uint_as_float(((uint32_t)h) << 16);
}

// ---------------- CSR build ----------------

__global__ void count_edges_k(const int* __restrict__ nl_dst, const int* __restrict__ ln_dst,
                              int* __restrict__ cnt_link, int* __restrict__ cnt_node) {
    int i = blockIdx.x * blockDim.x + threadIdx.x;
    int stride = gridDim.x * blockDim.x;
    for (; i < NEDGE; i += stride) {
        atomicAdd(&cnt_link[nl_dst[i]], 1);
        atomicAdd(&cnt_node[ln_dst[i]], 1);
    }
}

__global__ void scan_sums_k(const int* __restrict__ in, int n, int* __restrict__ bsums) {
    __shared__ int sd[256];
    int base = blockIdx.x * 1024;
    int s = 0;
    for (int i = threadIdx.x; i < 1024; i += 256) {
        int idx = base + i;
        if (idx < n) s += in[idx];
    }
    sd[threadIdx.x] = s;
    __syncthreads();
    for (int off = 128; off; off >>= 1) {
        if (threadIdx.x < off) sd[threadIdx.x] += sd[threadIdx.x + off];
        __syncthreads();
    }
    if (threadIdx.x == 0) bsums[blockIdx.x] = sd[0];
}

__global__ void scan_bsums_k(int* __restrict__ bsums, int nb) {
    __shared__ int tmp[2][1024];
    int t = threadIdx.x;
    int v = (t < nb) ? bsums[t] : 0;
    int src = 0;
    tmp[0][t] = v;
    __syncthreads();
    for (int off = 1; off < 1024; off <<= 1) {
        int nv = tmp[src][t] + ((t >= off) ? tmp[src][t - off] : 0);
        tmp[src ^ 1][t] = nv;
        __syncthreads();
        src ^= 1;
    }
    if (t < nb) bsums[t] = tmp[src][t] - v;  // exclusive
}

__global__ void scan_final_k(const int* __restrict__ in, int n, const int* __restrict__ bsums,
                             int* __restrict__ out, int total) {
    __shared__ int tmp[2][256];
    int b = blockIdx.x, t = threadIdx.x;
    int base = b * 1024 + t * 4;
    int vals[4];
    int s = 0;
#pragma unroll
    for (int j = 0; j < 4; ++j) {
        int idx = base + j;
        vals[j] = (idx < n) ? in[idx] : 0;
        s += vals[j];
    }
    tmp[0][t] = s;
    __syncthreads();
    int src = 0;
    for (int off = 1; off < 256; off <<= 1) {
        int nv = tmp[src][t] + ((t >= off) ? tmp[src][t - off] : 0);
        tmp[src ^ 1][t] = nv;
        __syncthreads();
        src ^= 1;
    }
    int run = bsums[b] + tmp[src][t] - s;
#pragma unroll
    for (int j = 0; j < 4; ++j) {
        int idx = base + j;
        if (idx < n) out[idx] = run;
        run += vals[j];
    }
    if (b == 0 && t == 0) out[n] = total;
}

__global__ void fill_csr_k(const int* __restrict__ dst, const int* __restrict__ src,
                           const int* __restrict__ rowp, int* __restrict__ cursor,
                           int* __restrict__ col) {
    int i = blockIdx.x * blockDim.x + threadIdx.x;
    int stride = gridDim.x * blockDim.x;
    for (; i < NEDGE; i += stride) {
        int d = dst[i];
        int pos = rowp[d] + atomicAdd(&cursor[d], 1);
        col[pos] = src[i];
    }
}

__global__ void inv_k(const int* __restrict__ cnt, float* __restrict__ inv, int n) {
    int i = blockIdx.x * blockDim.x + threadIdx.x;
    if (i < n) {
        int c = cnt[i];
        inv[i] = 1.0f / (float)(c > 0 ? c : 1);
    }
}

__global__ void batch_ranges_k(const int* __restrict__ batch, int* __restrict__ gstart,
                               float* __restrict__ ginv) {
    __shared__ int ss[NGRAPH + 1];
    int g = threadIdx.x;
    if (g <= NGRAPH) {
        int lo = 0, hi = NLINK;
        while (lo < hi) {
            int mid = (lo + hi) >> 1;
            if (batch[mid] < g) lo = mid + 1; else hi = mid;
        }
        ss[g] = lo;
        gstart[g] = lo;
    }
    __syncthreads();
    if (g < NGRAPH) {
        int c = ss[g + 1] - ss[g];
        ginv[g] = 1.0f / (float)(c > 0 ? c : 1);
    }
}

// ---------------- W fragment prep (split bf16, MFMA B-frag order) ----------------
// Wf index per matrix: ((ks*8 + nsub)*64 + lane)*8 + j  -> element W[k][col]
// with k = ks*32 + (lane>>4)*8 + j, col = nsub*16 + (lane&15)
__global__ void prep_w_k(const float* __restrict__ W_nl, const float* __restrict__ W_ln,
                         ushort* __restrict__ Whf, ushort* __restrict__ Wlf) {
    int mat = blockIdx.x;                  // mat = layer*2 + rel (rel 0=nl, 1=ln)
    int layer = mat >> 1, rel = mat & 1;
    const float* W = (rel ? W_ln : W_nl) + (size_t)layer * 2 * H * H;
    ushort* wh = Whf + (size_t)mat * 32768;
    ushort* wl = Wlf + (size_t)mat * 32768;
    for (int f = threadIdx.x; f < 32768; f += 256) {
        int j = f & 7;
        int lane = (f >> 3) & 63;
        int nsub = (f >> 9) & 7;
        int ks = f >> 12;
        int k = ks * 32 + (lane >> 4) * 8 + j;
        int col = nsub * 16 + (lane & 15);
        float w = W[(size_t)k * H + col];
        ushort hi = f2bf(w);
        ushort lo = f2bf(w - bf2f(hi));
        wh[f] = hi;
        wl[f] = lo;
    }
}

// ---------------- fused aggregate + split-bf16 MFMA linear + relu ----------------
// out[row,:] = relu( concat(mean xsrc[col[e]], xself[row]) @ W + b )
// 256 threads = 4 waves. Tile = 32 rows x K=256 -> N=128.
// Wave w computes rows 0..31 x cols [w*32, w*32+32) via 16x16x32 MFMA,
// 3 MFMAs per subtile per K-step (hh, hl, lh split-bf16).
__global__ __launch_bounds__(256) void update_mfma_k(
    const float* __restrict__ xsrc, const float* __restrict__ xself,
    const int* __restrict__ rowp, const int* __restrict__ colx,
    const float* __restrict__ invdeg,
    const ushort* __restrict__ wh, const ushort* __restrict__ wl,
    const float* __restrict__ bias, float* __restrict__ out, int ndst) {
    __shared__ ushort Ah[TS][256];   // 16 KB, XOR-swizzled 16B blocks
    __shared__ ushort Al[TS][256];   // 16 KB
    const int tid = threadIdx.x;
    const int lane = tid & 63;
    const int wave = tid >> 6;
    // phase-1 mapping: 32 lanes per row, float4 each
    const int l32 = tid & 31;
    const int rsub = tid >> 5;       // 0..7
    // phase-2 mapping
    const int l15 = lane & 15;
    const int lhi = lane >> 4;       // 0..3
    const float4* __restrict__ xsrc4 = reinterpret_cast<const float4*>(xsrc);
    const float4* __restrict__ xself4 = reinterpret_cast<const float4*>(xself);
    const bf16x8* __restrict__ wh8 = reinterpret_cast<const bf16x8*>(wh);
    const bf16x8* __restrict__ wl8 = reinterpret_cast<const bf16x8*>(wl);
    const float bv0 = bias[wave * 32 + l15];
    const float bv1 = bias[wave * 32 + 16 + l15];

    for (int t0 = blockIdx.x * TS; t0 < ndst; t0 += gridDim.x * TS) {
        // ---- phase 1: gather + split to bf16 hi/lo in LDS ----
#pragma unroll
        for (int j = 0; j < 4; ++j) {
            int rl = j * 8 + rsub;
            int row = t0 + rl;
            float4 av = {0.f, 0.f, 0.f, 0.f};
            float4 sv = {0.f, 0.f, 0.f, 0.f};
            if (row < ndst) {
                float ax = 0.f, ay = 0.f, az = 0.f, aw = 0.f;
                float bx = 0.f, by = 0.f, bz = 0.f, bw = 0.f;
                int e = rowp[row], re = rowp[row + 1];
                for (; e + 2 <= re; e += 2) {
                    int c0 = colx[e], c1 = colx[e + 1];
                    float4 v0 = xsrc4[(size_t)c0 * 32 + l32];
                    float4 v1 = xsrc4[(size_t)c1 * 32 + l32];
                    ax += v0.x; ay += v0.y; az += v0.z; aw += v0.w;
                    bx += v1.x; by += v1.y; bz += v1.z; bw += v1.w;
                }
                if (e < re) {
                    int c0 = colx[e];
                    float4 v0 = xsrc4[(size_t)c0 * 32 + l32];
                    ax += v0.x; ay += v0.y; az += v0.z; aw += v0.w;
                }
                float inv = invdeg[row];
                av.x = (ax + bx) * inv; av.y = (ay + by) * inv;
                av.z = (az + bz) * inv; av.w = (aw + bw) * inv;
                sv = xself4[(size_t)row * 32 + l32];
            }
            ushort4 h, l;
            h.x = f2bf(av.x); l.x = f2bf(av.x - bf2f(h.x));
            h.y = f2bf(av.y); l.y = f2bf(av.y - bf2f(h.y));
            h.z = f2bf(av.z); l.z = f2bf(av.z - bf2f(h.z));
            h.w = f2bf(av.w); l.w = f2bf(av.w - bf2f(h.w));
            int ob = rl * 512 + ((l32 * 8) ^ ((rl & 7) << 4));
            *reinterpret_cast<ushort4*>((char*)Ah + ob) = h;
            *reinterpret_cast<ushort4*>((char*)Al + ob) = l;
            h.x = f2bf(sv.x); l.x = f2bf(sv.x - bf2f(h.x));
            h.y = f2bf(sv.y); l.y = f2bf(sv.y - bf2f(h.y));
            h.z = f2bf(sv.z); l.z = f2bf(sv.z - bf2f(h.z));
            h.w = f2bf(sv.w); l.w = f2bf(sv.w - bf2f(h.w));
            int ob2 = rl * 512 + ((256 + l32 * 8) ^ ((rl & 7) << 4));
            *reinterpret_cast<ushort4*>((char*)Ah + ob2) = h;
            *reinterpret_cast<ushort4*>((char*)Al + ob2) = l;
        }
        __syncthreads();

        // ---- phase 2: MFMA 32x256 @ 256x128 (split bf16) ----
        f32x4 acc00 = {0.f, 0.f, 0.f, 0.f};
        f32x4 acc01 = {0.f, 0.f, 0.f, 0.f};
        f32x4 acc10 = {0.f, 0.f, 0.f, 0.f};
        f32x4 acc11 = {0.f, 0.f, 0.f, 0.f};
        const int swz = (l15 & 7) << 4;
#pragma unroll
        for (int ks = 0; ks < 8; ++ks) {
            int ko = ks * 64 + lhi * 16;
            int o0 = l15 * 512 + (ko ^ swz);
            int o1 = (l15 + 16) * 512 + (ko ^ swz);
            bf16x8 ah0 = *reinterpret_cast<const bf16x8*>((char*)Ah + o0);
            bf16x8 al0 = *reinterpret_cast<const bf16x8*>((char*)Al + o0);
            bf16x8 ah1 = *reinterpret_cast<const bf16x8*>((char*)Ah + o1);
            bf16x8 al1 = *reinterpret_cast<const bf16x8*>((char*)Al + o1);
            int fi0 = (ks * 8 + wave * 2) * 64 + lane;
            int fi1 = fi0 + 64;
            bf16x8 bh0 = wh8[fi0];
            bf16x8 bl0 = wl8[fi0];
            bf16x8 bh1 = wh8[fi1];
            bf16x8 bl1 = wl8[fi1];
            acc00 = __builtin_amdgcn_mfma_f32_16x16x32_bf16(ah0, bh0, acc00, 0, 0, 0);
            acc00 = __builtin_amdgcn_mfma_f32_16x16x32_bf16(ah0, bl0, acc00, 0, 0, 0);
            acc00 = __builtin_amdgcn_mfma_f32_16x16x32_bf16(al0, bh0, acc00, 0, 0, 0);
            acc01 = __builtin_amdgcn_mfma_f32_16x16x32_bf16(ah0, bh1, acc01, 0, 0, 0);
            acc01 = __builtin_amdgcn_mfma_f32_16x16x32_bf16(ah0, bl1, acc01, 0, 0, 0);
            acc01 = __builtin_amdgcn_mfma_f32_16x16x32_bf16(al0, bh1, acc01, 0, 0, 0);
            acc10 = __builtin_amdgcn_mfma_f32_16x16x32_bf16(ah1, bh0, acc10, 0, 0, 0);
            acc10 = __builtin_amdgcn_mfma_f32_16x16x32_bf16(ah1, bl0, acc10, 0, 0, 0);
            acc10 = __builtin_amdgcn_mfma_f32_16x16x32_bf16(al1, bh0, acc10, 0, 0, 0);
            acc11 = __builtin_amdgcn_mfma_f32_16x16x32_bf16(ah1, bh1, acc11, 0, 0, 0);
            acc11 = __builtin_amdgcn_mfma_f32_16x16x32_bf16(ah1, bl1, acc11, 0, 0, 0);
            acc11 = __builtin_amdgcn_mfma_f32_16x16x32_bf16(al1, bh1, acc11, 0, 0, 0);
        }

        // ---- epilogue: C/D layout col=lane&15, row=(lane>>4)*4+reg ----
#pragma unroll
        for (int reg = 0; reg < 4; ++reg) {
            int r0 = t0 + lhi * 4 + reg;
            if (r0 < ndst) {
                out[(size_t)r0 * H + wave * 32 + l15] = fmaxf(acc00[reg] + bv0, 0.f);
                out[(size_t)r0 * H + wave * 32 + 16 + l15] = fmaxf(acc01[reg] + bv1, 0.f);
            }
            int r1 = r0 + 16;
            if (r1 < ndst) {
                out[(size_t)r1 * H + wave * 32 + l15] = fmaxf(acc10[reg] + bv0, 0.f);
                out[(size_t)r1 * H + wave * 32 + 16 + l15] = fmaxf(acc11[reg] + bv1, 0.f);
            }
        }
        __syncthreads();
    }
}

// ---------------- final global mean pool over links ----------------
__global__ void pool_k(const float* __restrict__ xl, const int* __restrict__ gstart,
                       const float* __restrict__ ginv, float* __restrict__ out) {
    const int CH = 8;
    int g = blockIdx.x / CH, c = blockIdx.x % CH;
    int s = gstart[g], e = gstart[g + 1];
    int d = threadIdx.x & 127, h = threadIdx.x >> 7;
    float sum = 0.f;
    for (int l = s + c * 2 + h; l < e; l += CH * 2)
        sum += xl[(size_t)l * H + d];
    __shared__ float sm[256];
    sm[threadIdx.x] = sum;
    __syncthreads();
    if (h == 0) {
        float tot = sum + sm[128 + d];
        atomicAdd(&out[g * H + d], tot * ginv[g]);
    }
}

// ---------------- host ----------------

extern "C" void kernel_launch(void* const* d_in, const int* in_sizes, int n_in,
                              void* d_out, int out_size, void* d_ws, size_t ws_size,
                              hipStream_t stream) {
    const float* x_node = (const float*)d_in[0];
    const float* x_link = (const float*)d_in[1];
    const int* nl_src = (const int*)d_in[2];
    const int* nl_dst = (const int*)d_in[3];
    const int* ln_src = (const int*)d_in[4];
    const int* ln_dst = (const int*)d_in[5];
    const int* batch = (const int*)d_in[6];
    const float* W_nl = (const float*)d_in[7];
    const float* b_nl = (const float*)d_in[8];
    const float* W_ln = (const float*)d_in[9];
    const float* b_ln = (const float*)d_in[10];
    float* out = (float*)d_out;

    char* ws = (char*)d_ws;
    size_t off = 0;
    auto alloc = [&](size_t bytes) -> void* {
        void* p = ws + off;
        off += (bytes + 255) & ~(size_t)255;
        return p;
    };
    float* xl0 = (float*)alloc((size_t)NLINK * H * 4);
    float* xl1 = (float*)alloc((size_t)NLINK * H * 4);
    float* xn0 = (float*)alloc((size_t)NNODE * H * 4);
    float* xn1 = (float*)alloc((size_t)NNODE * H * 4);
    int* rowp_link = (int*)alloc((size_t)(NLINK + 1) * 4);
    int* rowp_node = (int*)alloc((size_t)(NNODE + 1) * 4);
    int* col_nl = (int*)alloc((size_t)NEDGE * 4);
    int* col_ln = (int*)alloc((size_t)NEDGE * 4);
    int* cnts = (int*)alloc((size_t)(2 * (NLINK + NNODE)) * 4);
    int* cnt_link = cnts;
    int* cnt_node = cnts + NLINK;
    int* cur_link = cnt_node + NNODE;
    int* cur_node = cur_link + NLINK;
    float* inv_link = (float*)alloc((size_t)NLINK * 4);
    float* inv_node = (float*)alloc((size_t)NNODE * 4);
    int* bsums = (int*)alloc(1024 * 4);
    int* gstart = (int*)alloc((NGRAPH + 1) * 4);
    float* ginv = (float*)alloc(NGRAPH * 4);
    ushort* Whf = (ushort*)alloc((size_t)8 * 32768 * 2);   // 8 mats, frag-ordered bf16 hi
    ushort* Wlf = (ushort*)alloc((size_t)8 * 32768 * 2);   // lo

    if (off > ws_size) return;

    hipMemsetAsync(cnts, 0, (size_t)(2 * (NLINK + NNODE)) * 4, stream);
    hipMemsetAsync(out, 0, (size_t)NGRAPH * H * 4, stream);

    prep_w_k<<<8, 256, 0, stream>>>(W_nl, W_ln, Whf, Wlf);

    count_edges_k<<<1024, 256, 0, stream>>>(nl_dst, ln_dst, cnt_link, cnt_node);

    int nbL = (NLINK + 1023) / 1024;
    scan_sums_k<<<nbL, 256, 0, stream>>>(cnt_link, NLINK, bsums);
    scan_bsums_k<<<1, 1024, 0, stream>>>(bsums, nbL);
    scan_final_k<<<nbL, 256, 0, stream>>>(cnt_link, NLINK, bsums, rowp_link, NEDGE);

    int nbN = (NNODE + 1023) / 1024;
    scan_sums_k<<<nbN, 256, 0, stream>>>(cnt_node, NNODE, bsums);
    scan_bsums_k<<<1, 1024, 0, stream>>>(bsums, nbN);
    scan_final_k<<<nbN, 256, 0, stream>>>(cnt_node, NNODE, bsums, rowp_node, NEDGE);

    inv_k<<<(NLINK + 255) / 256, 256, 0, stream>>>(cnt_link, inv_link, NLINK);
    inv_k<<<(NNODE + 255) / 256, 256, 0, stream>>>(cnt_node, inv_node, NNODE);

    fill_csr_k<<<1024, 256, 0, stream>>>(nl_dst, nl_src, rowp_link, cur_link, col_nl);
    fill_csr_k<<<1024, 256, 0, stream>>>(ln_dst, ln_src, rowp_node, cur_node, col_ln);

    batch_ranges_k<<<1, 64, 0, stream>>>(batch, gstart, ginv);

    const float* xlin = x_link;
    const float* xnin = x_node;
    float* xlb[2] = {xl0, xl1};
    float* xnb[2] = {xn0, xn1};
    for (int i = 0; i < NLAYER; ++i) {
        float* xlo = xlb[i & 1];
        float* xno = xnb[i & 1];
        int matL = i * 2 + 0;   // nl relation
        int matN = i * 2 + 1;   // ln relation
        update_mfma_k<<<(NLINK + TS - 1) / TS, 256, 0, stream>>>(
            xnin, xlin, rowp_link, col_nl, inv_link,
            Whf + (size_t)matL * 32768, Wlf + (size_t)matL * 32768,
            b_nl + (size_t)i * H, xlo, NLINK);
        update_mfma_k<<<(NNODE + TS - 1) / TS, 256, 0, stream>>>(
            xlin, xnin, rowp_node, col_ln, inv_node,
            Whf + (size_t)matN * 32768, Wlf + (size_t)matN * 32768,
            b_ln + (size_t)i * H, xno, NNODE);
        xlin = xlo;
        xnin = xno;
    }

    pool_k<<<NGRAPH * 8, 256, 0, stream>>>(xlin, gstart, ginv, out);
}

// Round 6
// 1021.238 us; speedup vs baseline: 2.5350x; 1.1866x over previous
//
#include <hip/hip_runtime.h>
#include <hip/hip_bf16.h>

#define H      128
#define NNODE  50000
#define NLINK  100000
#define NEDGE  600000
#define NGRAPH 32
#define NLAYER 4
#define ROUNDL 100032   // NLINK rounded to 64
#define ROUNDN 50048    // NNODE rounded to 64

typedef short  bf16x8 __attribute__((ext_vector_type(8)));
typedef ushort u16x8  __attribute__((ext_vector_type(8)));
typedef float  f32x4  __attribute__((ext_vector_type(4)));

__device__ __forceinline__ ushort f2bf(float f) {
    uint32_t u = __float_as_uint(f);
    uint32_t r = (u + 0x7fff + ((u >> 16) & 1)) >> 16;   // RNE
    return (ushort)r;
}
__device__ __forceinline__ float bf2f(ushort h) {
    return __uint_as_float(((uint32_t)h) << 16);
}
// split: hi = truncation (top 16 bits), lo = RNE(f - hi). |f - hi - lo| <= 2^-16 |f|
__device__ __forceinline__ ushort2 split2(float f) {
    uint32_t u = __float_as_uint(f);
    ushort hi = (ushort)(u >> 16);
    float r = f - __uint_as_float(u & 0xffff0000u);
    ushort2 out;
    out.x = hi;
    out.y = f2bf(r);
    return out;
}

// ---------------- CSR build ----------------

__global__ void count_edges_k(const int* __restrict__ nl_dst, const int* __restrict__ ln_dst,
                              int* __restrict__ cnt_link, int* __restrict__ cnt_node) {
    int i = blockIdx.x * blockDim.x + threadIdx.x;
    int stride = gridDim.x * blockDim.x;
    for (; i < NEDGE; i += stride) {
        atomicAdd(&cnt_link[nl_dst[i]], 1);
        atomicAdd(&cnt_node[ln_dst[i]], 1);
    }
}

// merged link+node block sums (1024 elems/block)
__global__ void scan_sums_k(const int* __restrict__ cnt_link, const int* __restrict__ cnt_node,
                            int* __restrict__ bsums, int nbL) {
    __shared__ int sd[256];
    int b = blockIdx.x;
    const int* in;
    int n, lb;
    if (b < nbL) { in = cnt_link; n = NLINK; lb = b; }
    else         { in = cnt_node; n = NNODE; lb = b - nbL; }
    int base = lb * 1024;
    int s = 0;
    for (int i = threadIdx.x; i < 1024; i += 256) {
        int idx = base + i;
        if (idx < n) s += in[idx];
    }
    sd[threadIdx.x] = s;
    __syncthreads();
    for (int off = 128; off; off >>= 1) {
        if (threadIdx.x < off) sd[threadIdx.x] += sd[threadIdx.x + off];
        __syncthreads();
    }
    if (threadIdx.x == 0) bsums[b] = sd[0];
}

// two independent exclusive scans over bsums[0,len0) and bsums[len0, len0+len1)
__global__ void scan_bsums2_k(int* __restrict__ bsums, int len0, int len1) {
    __shared__ int tmp[2][1024];
    int t = threadIdx.x;
    int base = 0;
    for (int seg = 0; seg < 2; ++seg) {
        int len = seg ? len1 : len0;
        int v = (t < len) ? bsums[base + t] : 0;
        tmp[0][t] = v;
        __syncthreads();
        int src = 0;
        for (int off = 1; off < 1024; off <<= 1) {
            int nv = tmp[src][t] + ((t >= off) ? tmp[src][t - off] : 0);
            tmp[src ^ 1][t] = nv;
            __syncthreads();
            src ^= 1;
        }
        if (t < len) bsums[base + t] = tmp[src][t] - v;   // exclusive
        __syncthreads();
        base += len0;
    }
}

__global__ void scan_final_k(const int* __restrict__ cnt_link, const int* __restrict__ cnt_node,
                             const int* __restrict__ bsums,
                             int* __restrict__ rowp_link, int* __restrict__ rowp_node, int nbL) {
    __shared__ int tmp[2][256];
    int b = blockIdx.x, t = threadIdx.x;
    const int* in;
    int* outp;
    int n, lb;
    if (b < nbL) { in = cnt_link; outp = rowp_link; n = NLINK; lb = b; }
    else         { in = cnt_node; outp = rowp_node; n = NNODE; lb = b - nbL; }
    int base = lb * 1024 + t * 4;
    int vals[4];
    int s = 0;
#pragma unroll
    for (int j = 0; j < 4; ++j) {
        int idx = base + j;
        vals[j] = (idx < n) ? in[idx] : 0;
        s += vals[j];
    }
    tmp[0][t] = s;
    __syncthreads();
    int src = 0;
    for (int off = 1; off < 256; off <<= 1) {
        int nv = tmp[src][t] + ((t >= off) ? tmp[src][t - off] : 0);
        tmp[src ^ 1][t] = nv;
        __syncthreads();
        src ^= 1;
    }
    int run = bsums[b] + tmp[src][t] - s;
#pragma unroll
    for (int j = 0; j < 4; ++j) {
        int idx = base + j;
        if (idx < n) outp[idx] = run;
        run += vals[j];
    }
    if (lb == 0 && t == 0) outp[n] = NEDGE;
}

__global__ void fill_csr2_k(const int* __restrict__ nl_dst, const int* __restrict__ nl_src,
                            const int* __restrict__ ln_dst, const int* __restrict__ ln_src,
                            const int* __restrict__ rowp_link, const int* __restrict__ rowp_node,
                            int* __restrict__ cur_link, int* __restrict__ cur_node,
                            int* __restrict__ col_nl, int* __restrict__ col_ln) {
    int half = gridDim.x >> 1;
    bool isL = blockIdx.x < half;
    const int* dst = isL ? nl_dst : ln_dst;
    const int* srcA = isL ? nl_src : ln_src;
    const int* rowp = isL ? rowp_link : rowp_node;
    int* cursor = isL ? cur_link : cur_node;
    int* col = isL ? col_nl : col_ln;
    int b = isL ? blockIdx.x : blockIdx.x - half;
    int i = b * 256 + threadIdx.x;
    int stride = half * 256;
    for (; i < NEDGE; i += stride) {
        int d = dst[i];
        int pos = rowp[d] + atomicAdd(&cursor[d], 1);
        col[pos] = srcA[i];
    }
}

__global__ void batch_ranges_k(const int* __restrict__ batch, int* __restrict__ gstart,
                               float* __restrict__ ginv) {
    __shared__ int ss[NGRAPH + 1];
    int g = threadIdx.x;
    if (g <= NGRAPH) {
        int lo = 0, hi = NLINK;
        while (lo < hi) {
            int mid = (lo + hi) >> 1;
            if (batch[mid] < g) lo = mid + 1; else hi = mid;
        }
        ss[g] = lo;
        gstart[g] = lo;
    }
    __syncthreads();
    if (g < NGRAPH) {
        int c = ss[g + 1] - ss[g];
        ginv[g] = 1.0f / (float)(c > 0 ? c : 1);
    }
}

// ---------------- fp32 -> swizzled bf16 hi/lo planes ----------------
// plane layout: row * 128 ushorts; 16B unit u stored at u' = u ^ (row & 7)
__global__ void split_k(const float* __restrict__ src, ushort* __restrict__ hi,
                        ushort* __restrict__ lo, int n) {
    int id = blockIdx.x * 256 + threadIdx.x;   // unit id
    if (id >= n * 16) return;
    int row = id >> 4, u = id & 15;
    const float4* s = reinterpret_cast<const float4*>(src + (size_t)row * H + u * 8);
    float4 v0 = s[0], v1 = s[1];
    u16x8 h8, l8;
    ushort2 r;
    r = split2(v0.x); h8[0] = r.x; l8[0] = r.y;
    r = split2(v0.y); h8[1] = r.x; l8[1] = r.y;
    r = split2(v0.z); h8[2] = r.x; l8[2] = r.y;
    r = split2(v0.w); h8[3] = r.x; l8[3] = r.y;
    r = split2(v1.x); h8[4] = r.x; l8[4] = r.y;
    r = split2(v1.y); h8[5] = r.x; l8[5] = r.y;
    r = split2(v1.z); h8[6] = r.x; l8[6] = r.y;
    r = split2(v1.w); h8[7] = r.x; l8[7] = r.y;
    int off = row * 128 + ((u ^ (row & 7)) << 3);
    *reinterpret_cast<u16x8*>(hi + off) = h8;
    *reinterpret_cast<u16x8*>(lo + off) = l8;
}

// ---------------- W fragment prep (split bf16, MFMA B-frag order) ----------------
__global__ void prep_w_k(const float* __restrict__ W_nl, const float* __restrict__ W_ln,
                         ushort* __restrict__ Whf, ushort* __restrict__ Wlf) {
    int mat = blockIdx.x;                  // mat = layer*2 + rel (rel 0=nl, 1=ln)
    int layer = mat >> 1, rel = mat & 1;
    const float* W = (rel ? W_ln : W_nl) + (size_t)layer * 2 * H * H;
    ushort* wh = Whf + (size_t)mat * 32768;
    ushort* wl = Wlf + (size_t)mat * 32768;
    for (int f = threadIdx.x; f < 32768; f += 256) {
        int j = f & 7;
        int lane = (f >> 3) & 63;
        int nsub = (f >> 9) & 7;
        int ks = f >> 12;
        int k = ks * 32 + (lane >> 4) * 8 + j;
        int col = nsub * 16 + (lane & 15);
        float w = W[(size_t)k * H + col];
        ushort hi = f2bf(w);
        ushort lo = f2bf(w - bf2f(hi));
        wh[f] = hi;
        wl[f] = lo;
    }
}

// ---------------- mean aggregation: CSR gather over hi/lo planes ----------------
__global__ __launch_bounds__(256) void agg_k(
    const ushort* __restrict__ shi, const ushort* __restrict__ slo,
    const int* __restrict__ rowp, const int* __restrict__ colx,
    ushort* __restrict__ dhi, ushort* __restrict__ dlo, int ndst) {
    int g = blockIdx.x * 16 + (threadIdx.x >> 4);
    int l16 = threadIdx.x & 15;
    if (g >= ndst) return;
    int rs = rowp[g], re = rowp[g + 1];
    float a[8] = {0.f, 0.f, 0.f, 0.f, 0.f, 0.f, 0.f, 0.f};
    int e = rs;
    for (; e + 2 <= re; e += 2) {
        int c0 = colx[e], c1 = colx[e + 1];
        size_t o0 = (size_t)c0 * 128 + ((l16 ^ (c0 & 7)) << 3);
        size_t o1 = (size_t)c1 * 128 + ((l16 ^ (c1 & 7)) << 3);
        u16x8 h0 = *reinterpret_cast<const u16x8*>(shi + o0);
        u16x8 l0 = *reinterpret_cast<const u16x8*>(slo + o0);
        u16x8 h1 = *reinterpret_cast<const u16x8*>(shi + o1);
        u16x8 l1 = *reinterpret_cast<const u16x8*>(slo + o1);
#pragma unroll
        for (int j = 0; j < 8; ++j)
            a[j] += (bf2f(h0[j]) + bf2f(l0[j])) + (bf2f(h1[j]) + bf2f(l1[j]));
    }
    if (e < re) {
        int c0 = colx[e];
        size_t o0 = (size_t)c0 * 128 + ((l16 ^ (c0 & 7)) << 3);
        u16x8 h0 = *reinterpret_cast<const u16x8*>(shi + o0);
        u16x8 l0 = *reinterpret_cast<const u16x8*>(slo + o0);
#pragma unroll
        for (int j = 0; j < 8; ++j)
            a[j] += bf2f(h0[j]) + bf2f(l0[j]);
    }
    int c = re - rs;
    float inv = 1.0f / (float)(c > 0 ? c : 1);
    u16x8 h8, l8;
#pragma unroll
    for (int j = 0; j < 8; ++j) {
        ushort2 hl = split2(a[j] * inv);
        h8[j] = hl.x; l8[j] = hl.y;
    }
    int off = g * 128 + ((l16 ^ (g & 7)) << 3);
    *reinterpret_cast<u16x8*>(dhi + off) = h8;
    *reinterpret_cast<u16x8*>(dlo + off) = l8;
}

// ---------------- GEMM: relu([agg | self] @ W + b), split-bf16 MFMA ----------------
// 64-row tile, 256 thr / 4 waves; wave w stages plane w via global_load_lds and
// computes cols [w*32, w*32+32). A planes are pre-swizzled (unit ^= row&7).
// Staging: one global_load_lds(16B) covers 64 lanes x 16B = 1024 B = 512 ushorts.
__global__ __launch_bounds__(256) void gemm_k(
    const ushort* __restrict__ ahi, const ushort* __restrict__ alo,
    const ushort* __restrict__ shi, const ushort* __restrict__ slo,
    const ushort* __restrict__ wh, const ushort* __restrict__ wl,
    const float* __restrict__ bias,
    ushort* __restrict__ ohi, ushort* __restrict__ olo, int ndst) {
    __shared__ ushort A[4][64 * 128];   // 4 planes x 16KB
    const int tid = threadIdx.x;
    const int lane = tid & 63;
    const int wave = tid >> 6;
    const int l15 = lane & 15;
    const int lhi = lane >> 4;
    const int t0 = blockIdx.x * 64;

    const ushort* p = (wave == 0) ? ahi : (wave == 1) ? alo : (wave == 2) ? shi : slo;
    const ushort* gsrc = p + (size_t)t0 * 128;
#pragma unroll
    for (int i = 0; i < 16; ++i) {
        __builtin_amdgcn_global_load_lds(
            (const __attribute__((address_space(1))) void*)(gsrc + i * 512 + lane * 8),
            (__attribute__((address_space(3))) void*)(&A[wave][i * 512]), 16, 0, 0);
    }
    __syncthreads();

    f32x4 acc[4][2];
#pragma unroll
    for (int rs = 0; rs < 4; ++rs)
#pragma unroll
        for (int c = 0; c < 2; ++c)
            acc[rs][c] = (f32x4){0.f, 0.f, 0.f, 0.f};

    const bf16x8* __restrict__ wh8 = reinterpret_cast<const bf16x8*>(wh);
    const bf16x8* __restrict__ wl8 = reinterpret_cast<const bf16x8*>(wl);

#pragma unroll
    for (int ks = 0; ks < 8; ++ks) {
        const int ph = (ks < 4) ? 0 : 2;
        const int ub = (ks & 3) * 4 + lhi;
        bf16x8 ah[4], al[4];
#pragma unroll
        for (int rs = 0; rs < 4; ++rs) {
            int row = rs * 16 + l15;
            int off = row * 128 + ((ub ^ (row & 7)) << 3);
            ah[rs] = *reinterpret_cast<const bf16x8*>(&A[ph][off]);
            al[rs] = *reinterpret_cast<const bf16x8*>(&A[ph + 1][off]);
        }
        int fi = (ks * 8 + wave * 2) * 64 + lane;
        bf16x8 bh0 = wh8[fi], bl0 = wl8[fi];
        bf16x8 bh1 = wh8[fi + 64], bl1 = wl8[fi + 64];
#pragma unroll
        for (int rs = 0; rs < 4; ++rs) {
            acc[rs][0] = __builtin_amdgcn_mfma_f32_16x16x32_bf16(ah[rs], bh0, acc[rs][0], 0, 0, 0);
            acc[rs][0] = __builtin_amdgcn_mfma_f32_16x16x32_bf16(ah[rs], bl0, acc[rs][0], 0, 0, 0);
            acc[rs][0] = __builtin_amdgcn_mfma_f32_16x16x32_bf16(al[rs], bh0, acc[rs][0], 0, 0, 0);
            acc[rs][1] = __builtin_amdgcn_mfma_f32_16x16x32_bf16(ah[rs], bh1, acc[rs][1], 0, 0, 0);
            acc[rs][1] = __builtin_amdgcn_mfma_f32_16x16x32_bf16(ah[rs], bl1, acc[rs][1], 0, 0, 0);
            acc[rs][1] = __builtin_amdgcn_mfma_f32_16x16x32_bf16(al[rs], bh1, acc[rs][1], 0, 0, 0);
        }
    }

    const float bv0 = bias[wave * 32 + l15];
    const float bv1 = bias[wave * 32 + 16 + l15];
#pragma unroll
    for (int rs = 0; rs < 4; ++rs) {
#pragma unroll
        for (int c = 0; c < 2; ++c) {
            int col = wave * 32 + c * 16 + l15;
            float bb = c ? bv1 : bv0;
            int unit = col >> 3;
            int cpos = col & 7;
#pragma unroll
            for (int reg = 0; reg < 4; ++reg) {
                int row = t0 + rs * 16 + lhi * 4 + reg;
                if (row < ndst) {
                    float v = fmaxf(acc[rs][c][reg] + bb, 0.f);
                    ushort2 hl = split2(v);
                    int off = row * 128 + ((unit ^ (row & 7)) << 3) + cpos;
                    ohi[off] = hl.x;
                    olo[off] = hl.y;
                }
            }
        }
    }
}

// ---------------- final global mean pool over links ----------------
__global__ __launch_bounds__(256) void pool_k(
    const ushort* __restrict__ xhi, const ushort* __restrict__ xlo,
    const int* __restrict__ gstart, const float* __restrict__ ginv,
    float* __restrict__ out) {
    int g = blockIdx.x >> 3, chunk = blockIdx.x & 7;
    int s = gstart[g], e = gstart[g + 1];
    int rl = threadIdx.x >> 4, l16 = threadIdx.x & 15;
    float a[8] = {0.f, 0.f, 0.f, 0.f, 0.f, 0.f, 0.f, 0.f};
    for (int r = s + chunk * 16 + rl; r < e; r += 128) {
        int off = r * 128 + ((l16 ^ (r & 7)) << 3);
        u16x8 h = *reinterpret_cast<const u16x8*>(xhi + off);
        u16x8 l = *reinterpret_cast<const u16x8*>(xlo + off);
#pragma unroll
        for (int j = 0; j < 8; ++j) a[j] += bf2f(h[j]) + bf2f(l[j]);
    }
    __shared__ float sm[16][128];
#pragma unroll
    for (int j = 0; j < 8; ++j) sm[rl][l16 * 8 + j] = a[j];
    __syncthreads();
    for (int st = 8; st; st >>= 1) {
        if (rl < st) {
#pragma unroll
            for (int j = 0; j < 8; ++j)
                sm[rl][l16 * 8 + j] += sm[rl + st][l16 * 8 + j];
        }
        __syncthreads();
    }
    if (rl == 0) {
        float gi = ginv[g];
#pragma unroll
        for (int j = 0; j < 8; ++j)
            atomicAdd(&out[g * H + l16 * 8 + j], sm[0][l16 * 8 + j] * gi);
    }
}

// ---------------- host ----------------

extern "C" void kernel_launch(void* const* d_in, const int* in_sizes, int n_in,
                              void* d_out, int out_size, void* d_ws, size_t ws_size,
                              hipStream_t stream) {
    const float* x_node = (const float*)d_in[0];
    const float* x_link = (const float*)d_in[1];
    const int* nl_src = (const int*)d_in[2];
    const int* nl_dst = (const int*)d_in[3];
    const int* ln_src = (const int*)d_in[4];
    const int* ln_dst = (const int*)d_in[5];
    const int* batch = (const int*)d_in[6];
    const float* W_nl = (const float*)d_in[7];
    const float* b_nl = (const float*)d_in[8];
    const float* W_ln = (const float*)d_in[9];
    const float* b_ln = (const float*)d_in[10];
    float* out = (float*)d_out;

    char* ws = (char*)d_ws;
    size_t off = 0;
    auto alloc = [&](size_t bytes) -> void* {
        void* pp = ws + off;
        off += (bytes + 255) & ~(size_t)255;
        return pp;
    };
    const size_t LP = (size_t)ROUNDL * H * 2;   // link plane bytes
    const size_t NP = (size_t)ROUNDN * H * 2;   // node plane bytes
    ushort* xlh[2] = {(ushort*)alloc(LP), (ushort*)alloc(LP)};
    ushort* xll[2] = {(ushort*)alloc(LP), (ushort*)alloc(LP)};
    ushort* xnh[2] = {(ushort*)alloc(NP), (ushort*)alloc(NP)};
    ushort* xnl[2] = {(ushort*)alloc(NP), (ushort*)alloc(NP)};
    int* rowp_link = (int*)alloc((size_t)(NLINK + 1) * 4);
    int* rowp_node = (int*)alloc((size_t)(NNODE + 1) * 4);
    int* col_nl = (int*)alloc((size_t)NEDGE * 4);
    int* col_ln = (int*)alloc((size_t)NEDGE * 4);
    int* cnts = (int*)alloc((size_t)(2 * (NLINK + NNODE)) * 4);
    int* cnt_link = cnts;
    int* cnt_node = cnts + NLINK;
    int* cur_link = cnt_node + NNODE;
    int* cur_node = cur_link + NLINK;
    int* bsums = (int*)alloc(1024 * 4);
    int* gstart = (int*)alloc((NGRAPH + 1) * 4);
    float* ginv = (float*)alloc(NGRAPH * 4);
    ushort* Whf = (ushort*)alloc((size_t)8 * 32768 * 2);
    ushort* Wlf = (ushort*)alloc((size_t)8 * 32768 * 2);

    if (off > ws_size) return;

    hipMemsetAsync(cnts, 0, (size_t)(2 * (NLINK + NNODE)) * 4, stream);
    hipMemsetAsync(out, 0, (size_t)NGRAPH * H * 4, stream);

    prep_w_k<<<8, 256, 0, stream>>>(W_nl, W_ln, Whf, Wlf);

    split_k<<<NLINK * 16 / 256, 256, 0, stream>>>(x_link, xlh[0], xll[0], NLINK);
    split_k<<<NNODE * 16 / 256, 256, 0, stream>>>(x_node, xnh[0], xnl[0], NNODE);

    count_edges_k<<<1024, 256, 0, stream>>>(nl_dst, ln_dst, cnt_link, cnt_node);

    const int nbL = (NLINK + 1023) / 1024;   // 98
    const int nbN = (NNODE + 1023) / 1024;   // 49
    scan_sums_k<<<nbL + nbN, 256, 0, stream>>>(cnt_link, cnt_node, bsums, nbL);
    scan_bsums2_k<<<1, 1024, 0, stream>>>(bsums, nbL, nbN);
    scan_final_k<<<nbL + nbN, 256, 0, stream>>>(cnt_link, cnt_node, bsums,
                                                rowp_link, rowp_node, nbL);

    fill_csr2_k<<<2048, 256, 0, stream>>>(nl_dst, nl_src, ln_dst, ln_src,
                                          rowp_link, rowp_node, cur_link, cur_node,
                                          col_nl, col_ln);

    batch_ranges_k<<<1, 64, 0, stream>>>(batch, gstart, ginv);

    int cur = 0;
    for (int i = 0; i < NLAYER; ++i) {
        int nxt = cur ^ 1;
        int matL = i * 2 + 0;
        int matN = i * 2 + 1;
        // link relation: agg from node feats -> in-place into link output buffer
        agg_k<<<(NLINK + 15) / 16, 256, 0, stream>>>(
            xnh[cur], xnl[cur], rowp_link, col_nl, xlh[nxt], xll[nxt], NLINK);
        gemm_k<<<ROUNDL / 64, 256, 0, stream>>>(
            xlh[nxt], xll[nxt], xlh[cur], xll[cur],
            Whf + (size_t)matL * 32768, Wlf + (size_t)matL * 32768,
            b_nl + (size_t)i * H, xlh[nxt], xll[nxt], NLINK);
        // node relation: agg from OLD link feats (xl*[cur]) -> node output buffer
        agg_k<<<(NNODE + 15) / 16, 256, 0, stream>>>(
            xlh[cur], xll[cur], rowp_node, col_ln, xnh[nxt], xnl[nxt], NNODE);
        gemm_k<<<ROUNDN / 64, 256, 0, stream>>>(
            xnh[nxt], xnl[nxt], xnh[cur], xnl[cur],
            Whf + (size_t)matN * 32768, Wlf + (size_t)matN * 32768,
            b_ln + (size_t)i * H, xnh[nxt], xnl[nxt], NNODE);
        cur = nxt;
    }

    pool_k<<<NGRAPH * 8, 256, 0, stream>>>(xlh[cur], xll[cur], gstart, ginv, out);
}